// Round 1
// baseline (521.918 us; speedup 1.0000x reference)
//
#include <hip/hip_runtime.h>
#include <math.h>

#define H_DIM 256
#define HEADS 4
#define HD 64
#define TOPK 15
#define NSLOPE 0.2

// wa_dst[h][k] = sum_d W[(h*64+d)*256+k] * att[h*128+d]      (a_dst)
// wa_src[h][k] = sum_d W[(h*64+d)*256+k] * att[h*128+64+d]   (a_src)
__global__ void wa_kernel(const float* __restrict__ W, const float* __restrict__ att,
                          double* __restrict__ wa_dst, double* __restrict__ wa_src) {
    int k = threadIdx.x;  // 0..255
    for (int h = 0; h < HEADS; ++h) {
        double ad = 0.0, as = 0.0;
        for (int d = 0; d < HD; ++d) {
            double wv = (double)W[(h * HD + d) * H_DIM + k];
            ad += wv * (double)att[h * 2 * HD + d];
            as += wv * (double)att[h * 2 * HD + HD + d];
        }
        wa_dst[h * H_DIM + k] = ad;
        wa_src[h * H_DIM + k] = as;
    }
}

// s_dst[i][h] = emb[i,:] . wa_dst[h,:]   (block per row, 256 threads)
__global__ __launch_bounds__(256) void s_kernel(const float* __restrict__ emb,
                                                const double* __restrict__ wa_dst,
                                                const double* __restrict__ wa_src,
                                                double* __restrict__ s_dst,
                                                double* __restrict__ s_src) {
    int i = blockIdx.x;
    int t = threadIdx.x;
    __shared__ double red[256];
    double e = (double)emb[(size_t)i * H_DIM + t];
    for (int h = 0; h < HEADS; ++h) {
        red[t] = e * wa_dst[h * H_DIM + t];
        __syncthreads();
        for (int s = 128; s > 0; s >>= 1) {
            if (t < s) red[t] += red[t + s];
            __syncthreads();
        }
        if (t == 0) s_dst[i * HEADS + h] = red[0];
        __syncthreads();
        red[t] = e * wa_src[h * H_DIM + t];
        __syncthreads();
        for (int s = 128; s > 0; s >>= 1) {
            if (t < s) red[t] += red[t + s];
            __syncthreads();
        }
        if (t == 0) s_src[i * HEADS + h] = red[0];
        __syncthreads();
    }
}

__global__ void count_kernel(const int* __restrict__ eidx, int* __restrict__ row_cnt, int E) {
    int e = blockIdx.x * 256 + threadIdx.x;
    if (e < E) atomicAdd(&row_cnt[eidx[e]], 1);
}

// exclusive prefix sum of 4096 counts -> row_off[0..N], single block of 256
__global__ void scan_kernel(const int* __restrict__ row_cnt, int* __restrict__ row_off, int N) {
    __shared__ int lds[4096];
    __shared__ int part[256];
    int t = threadIdx.x;
    int s = 0;
    for (int k = 0; k < 16; ++k) {
        int v = row_cnt[t * 16 + k];
        lds[t * 16 + k] = v;
        s += v;
    }
    part[t] = s;
    __syncthreads();
    if (t == 0) {
        int a = 0;
        for (int u = 0; u < 256; ++u) { int v = part[u]; part[u] = a; a += v; }
    }
    __syncthreads();
    int run = part[t];
    for (int k = 0; k < 16; ++k) {
        row_off[t * 16 + k] = run;
        run += lds[t * 16 + k];
    }
    if (t == 255) row_off[N] = run;
}

__global__ void fill_kernel(const int* __restrict__ eidx, const float* __restrict__ ew,
                            const int* __restrict__ row_off, int* __restrict__ fill_cnt,
                            int* __restrict__ csr_col, int* __restrict__ csr_eid,
                            float* __restrict__ csr_w, int E) {
    int e = blockIdx.x * 256 + threadIdx.x;
    if (e < E) {
        int r = eidx[e];
        int c = eidx[E + e];
        int p = row_off[r] + atomicAdd(&fill_cnt[r], 1);
        csr_col[p] = c;
        csr_eid[p] = e;
        csr_w[p] = ew[e];
    }
}

// One block per row i: compute 4096 scores into LDS (fp64), apply corr edges
// (last-write-wins by edge id), iterative top-15 argmax, softmax, write out.
__global__ __launch_bounds__(256) void main_kernel(
    const double* __restrict__ s_dst, const double* __restrict__ s_src,
    const int* __restrict__ sector_mask, const int* __restrict__ active,
    const float* __restrict__ lam_p, const int* __restrict__ row_off,
    const int* __restrict__ csr_col, const int* __restrict__ csr_eid,
    const float* __restrict__ csr_w, float* __restrict__ out, int N) {
    const int i = blockIdx.x;
    const int tid = threadIdx.x;
    __shared__ double sc[4096];
    __shared__ int eidm[4096];
    __shared__ double rv[256];
    __shared__ int ri[256];
    __shared__ double topv[TOPK];
    __shared__ int topi[TOPK];
    __shared__ double ssum;

    const double sd0 = s_dst[i * 4 + 0];
    const double sd1 = s_dst[i * 4 + 1];
    const double sd2 = s_dst[i * 4 + 2];
    const double sd3 = s_dst[i * 4 + 3];
    const bool ai = (active[i] != 0);
    const double lam = (double)lam_p[0];
    const size_t rowbase = (size_t)i * (size_t)N;

    for (int j = tid; j < N; j += 256) {
        bool m = ai && (active[j] != 0) && (sector_mask[rowbase + j] != 0);
        double v;
        if (m) {
            double x0 = sd0 + s_src[j * 4 + 0];
            double x1 = sd1 + s_src[j * 4 + 1];
            double x2 = sd2 + s_src[j * 4 + 2];
            double x3 = sd3 + s_src[j * 4 + 3];
            x0 = (x0 < 0.0) ? NSLOPE * x0 : x0;
            x1 = (x1 < 0.0) ? NSLOPE * x1 : x1;
            x2 = (x2 < 0.0) ? NSLOPE * x2 : x2;
            x3 = (x3 < 0.0) ? NSLOPE * x3 : x3;
            v = 0.25 * (x0 + x1 + x2 + x3);
        } else {
            v = -INFINITY;
        }
        sc[j] = v;
        eidm[j] = -1;
    }
    __syncthreads();

    const int rs = row_off[i], re = row_off[i + 1];
    for (int p = rs + tid; p < re; p += 256) {
        atomicMax(&eidm[csr_col[p]], csr_eid[p]);
    }
    __syncthreads();
    for (int p = rs + tid; p < re; p += 256) {
        int c = csr_col[p];
        if (eidm[c] == csr_eid[p]) sc[c] += lam * (double)csr_w[p];  // -inf stays -inf
    }
    __syncthreads();

    for (int it = 0; it < TOPK; ++it) {
        double bv = -INFINITY;
        int bi = N;
        for (int j = tid; j < N; j += 256) {
            double v = sc[j];
            if (v > bv || (v == bv && j < bi)) { bv = v; bi = j; }
        }
        rv[tid] = bv;
        ri[tid] = bi;
        __syncthreads();
        for (int s = 128; s > 0; s >>= 1) {
            if (tid < s) {
                if (rv[tid + s] > rv[tid] || (rv[tid + s] == rv[tid] && ri[tid + s] < ri[tid])) {
                    rv[tid] = rv[tid + s];
                    ri[tid] = ri[tid + s];
                }
            }
            __syncthreads();
        }
        if (tid == 0) {
            topv[it] = rv[0];
            topi[it] = ri[0];
            sc[ri[0]] = -INFINITY;
        }
        __syncthreads();
    }

    if (tid == 0) {
        double m = topv[0], s = 0.0;
        for (int t = 0; t < TOPK; ++t) s += exp(topv[t] - m);
        ssum = s;
    }
    __syncthreads();

    if (tid < TOPK) {
        const int NK = N * TOPK;
        int base = i * TOPK + tid;
        double w = exp(topv[tid] - topv[0]) / ssum;
        out[base] = (float)topi[tid];          // edge_index row 0: topk column idx
        out[NK + base] = (float)i;             // edge_index row 1: source row
        out[2 * NK + base] = (float)w;         // edge_weight (softmax)
    }
}

extern "C" void kernel_launch(void* const* d_in, const int* in_sizes, int n_in,
                              void* d_out, int out_size, void* d_ws, size_t ws_size,
                              hipStream_t stream) {
    const float* emb    = (const float*)d_in[0];
    const float* W      = (const float*)d_in[1];
    const float* att    = (const float*)d_in[2];
    const float* lam    = (const float*)d_in[3];
    const int*   sector = (const int*)d_in[4];
    const int*   active = (const int*)d_in[5];
    const int*   eidx   = (const int*)d_in[6];
    const float* ew     = (const float*)d_in[7];
    float* out = (float*)d_out;

    const int N = in_sizes[5];      // 4096
    const int E = in_sizes[6] / 2;  // 131072

    // workspace layout (doubles first, then ints)
    double* wa_dst = (double*)d_ws;
    double* wa_src = wa_dst + HEADS * H_DIM;
    double* s_dst  = wa_src + HEADS * H_DIM;
    double* s_src  = s_dst + (size_t)N * HEADS;
    int* row_cnt   = (int*)(s_src + (size_t)N * HEADS);
    int* fill_cnt  = row_cnt + N;
    int* row_off   = fill_cnt + N;
    int* csr_col   = row_off + (N + 2);
    int* csr_eid   = csr_col + E;
    float* csr_w   = (float*)(csr_eid + E);

    hipMemsetAsync(row_cnt, 0, (size_t)2 * N * sizeof(int), stream);  // row_cnt + fill_cnt

    wa_kernel<<<1, 256, 0, stream>>>(W, att, wa_dst, wa_src);
    s_kernel<<<N, 256, 0, stream>>>(emb, wa_dst, wa_src, s_dst, s_src);
    count_kernel<<<(E + 255) / 256, 256, 0, stream>>>(eidx, row_cnt, E);
    scan_kernel<<<1, 256, 0, stream>>>(row_cnt, row_off, N);
    fill_kernel<<<(E + 255) / 256, 256, 0, stream>>>(eidx, ew, row_off, fill_cnt,
                                                     csr_col, csr_eid, csr_w, E);
    main_kernel<<<N, 256, 0, stream>>>(s_dst, s_src, sector, active, lam, row_off,
                                       csr_col, csr_eid, csr_w, out, N);
}

// Round 2
// 389.202 us; speedup vs baseline: 1.3410x; 1.3410x over previous
//
#include <hip/hip_runtime.h>
#include <math.h>

#define H_DIM 256
#define HEADS 4
#define HD 64
#define TOPK 15
#define NSLOPE 0.2

// wa_dst[h][k] = sum_d W[(h*64+d)*256+k] * att[h*128+d]      (a_dst)
// wa_src[h][k] = sum_d W[(h*64+d)*256+k] * att[h*128+64+d]   (a_src)
__global__ void wa_kernel(const float* __restrict__ W, const float* __restrict__ att,
                          double* __restrict__ wa_dst, double* __restrict__ wa_src) {
    int k = threadIdx.x;  // 0..255
    for (int h = 0; h < HEADS; ++h) {
        double ad = 0.0, as = 0.0;
        for (int d = 0; d < HD; ++d) {
            double wv = (double)W[(h * HD + d) * H_DIM + k];
            ad += wv * (double)att[h * 2 * HD + d];
            as += wv * (double)att[h * 2 * HD + HD + d];
        }
        wa_dst[h * H_DIM + k] = ad;
        wa_src[h * H_DIM + k] = as;
    }
}

// One wave per row: 8 dot-products of length 256 via shuffle reduce, no barriers.
__global__ __launch_bounds__(256) void s_kernel(const float* __restrict__ emb,
                                                const double* __restrict__ wa_dst,
                                                const double* __restrict__ wa_src,
                                                double* __restrict__ s_dst,
                                                double* __restrict__ s_src) {
    const int lane = threadIdx.x & 63;
    const int wid = threadIdx.x >> 6;
    const int i = blockIdx.x * 4 + wid;
    double e[4];
#pragma unroll
    for (int m = 0; m < 4; ++m) e[m] = (double)emb[(size_t)i * H_DIM + lane + 64 * m];
#pragma unroll
    for (int combo = 0; combo < 8; ++combo) {
        const int h = combo >> 1;
        const double* wa = (combo & 1) ? wa_src : wa_dst;
        double acc = 0.0;
#pragma unroll
        for (int m = 0; m < 4; ++m) acc += e[m] * wa[h * H_DIM + lane + 64 * m];
#pragma unroll
        for (int m = 1; m < 64; m <<= 1) acc += __shfl_xor(acc, m, 64);
        if (lane == 0) {
            if (combo & 1) s_src[i * HEADS + h] = acc;
            else           s_dst[i * HEADS + h] = acc;
        }
    }
}

__global__ void count_kernel(const int* __restrict__ eidx, int* __restrict__ row_cnt, int E) {
    int e = blockIdx.x * 256 + threadIdx.x;
    if (e < E) atomicAdd(&row_cnt[eidx[e]], 1);
}

// exclusive prefix sum of 4096 counts -> row_off[0..N], single block of 256
__global__ void scan_kernel(const int* __restrict__ row_cnt, int* __restrict__ row_off, int N) {
    __shared__ int lds[4096];
    __shared__ int part[256];
    int t = threadIdx.x;
    int s = 0;
    for (int k = 0; k < 16; ++k) {
        int v = row_cnt[t * 16 + k];
        lds[t * 16 + k] = v;
        s += v;
    }
    part[t] = s;
    __syncthreads();
    if (t == 0) {
        int a = 0;
        for (int u = 0; u < 256; ++u) { int v = part[u]; part[u] = a; a += v; }
    }
    __syncthreads();
    int run = part[t];
    for (int k = 0; k < 16; ++k) {
        row_off[t * 16 + k] = run;
        run += lds[t * 16 + k];
    }
    if (t == 255) row_off[N] = run;
}

__global__ void fill_kernel(const int* __restrict__ eidx, const float* __restrict__ ew,
                            const int* __restrict__ row_off, int* __restrict__ fill_cnt,
                            int* __restrict__ csr_col, int* __restrict__ csr_eid,
                            float* __restrict__ csr_w, int E) {
    int e = blockIdx.x * 256 + threadIdx.x;
    if (e < E) {
        int r = eidx[e];
        int c = eidx[E + e];
        int p = row_off[r] + atomicAdd(&fill_cnt[r], 1);
        csr_col[p] = c;
        csr_eid[p] = e;
        csr_w[p] = ew[e];
    }
}

// One block per row. Scores live in 16 registers per thread (thread owns
// columns j = tid + 256k). Corr edges routed to owning thread; top-15 via
// cached local max + shuffle butterfly + 4-way cross-wave merge (2 barriers/iter).
__global__ __launch_bounds__(256) void main_kernel(
    const double* __restrict__ s_dst, const double* __restrict__ s_src,
    const int* __restrict__ sector_mask, const int* __restrict__ active,
    const float* __restrict__ lam_p, const int* __restrict__ row_off,
    const int* __restrict__ csr_col, const int* __restrict__ csr_eid,
    const float* __restrict__ csr_w, float* __restrict__ out, int N) {
    const int i = blockIdx.x;
    const int tid = threadIdx.x;
    const int lane = tid & 63;
    const int wid = tid >> 6;

    __shared__ double wv[4];
    __shared__ int wi4[4];
    __shared__ double topvS[TOPK];
    __shared__ int topiS[TOPK];
    __shared__ double ssum;

    const double sd0 = s_dst[i * 4 + 0];
    const double sd1 = s_dst[i * 4 + 1];
    const double sd2 = s_dst[i * 4 + 2];
    const double sd3 = s_dst[i * 4 + 3];
    const bool ai = (active[i] != 0);
    const double lam = (double)lam_p[0];
    const size_t rowbase = (size_t)i * (size_t)N;

    // Phase 1: scores into registers
    double v[16];
#pragma unroll
    for (int k = 0; k < 16; ++k) {
        const int j = tid + (k << 8);
        bool m = ai && (active[j] != 0) && (sector_mask[rowbase + j] != 0);
        if (m) {
            double x0 = sd0 + s_src[j * 4 + 0];
            double x1 = sd1 + s_src[j * 4 + 1];
            double x2 = sd2 + s_src[j * 4 + 2];
            double x3 = sd3 + s_src[j * 4 + 3];
            x0 = (x0 < 0.0) ? NSLOPE * x0 : x0;
            x1 = (x1 < 0.0) ? NSLOPE * x1 : x1;
            x2 = (x2 < 0.0) ? NSLOPE * x2 : x2;
            x3 = (x3 < 0.0) ? NSLOPE * x3 : x3;
            v[k] = 0.25 * (x0 + x1 + x2 + x3);
        } else {
            v[k] = -INFINITY;   // -inf + corr stays -inf (matches corr*mask)
        }
    }

    // Phase 2: corr edges (last-write-wins by edge id; O(deg^2) dedup, deg~32)
    const int rs = row_off[i], re = row_off[i + 1];
    for (int p = rs; p < re; ++p) {
        const int c = csr_col[p];
        if ((c & 255) == tid) {
            const int eid = csr_eid[p];
            bool win = true;
            for (int q = rs; q < re; ++q)
                if (csr_col[q] == c && csr_eid[q] > eid) win = false;
            if (win) {
                const double add = lam * (double)csr_w[p];
                const int k = c >> 8;
#pragma unroll
                for (int kk = 0; kk < 16; ++kk)
                    if (kk == k) v[kk] += add;
            }
        }
    }

    // Phase 3: cached per-thread local max
    unsigned int emask = 0;  // extracted-slot bitmask
    double lv = -INFINITY;
    int li = 0x7fffffff;
#pragma unroll
    for (int k = 0; k < 16; ++k) {
        const int j = tid + (k << 8);
        if (v[k] > lv || (v[k] == lv && j < li)) { lv = v[k]; li = j; }
    }

    for (int it = 0; it < TOPK; ++it) {
        // wave butterfly argmax (ties -> smaller index)
        double bv = lv;
        int bi = li;
#pragma unroll
        for (int m = 1; m < 64; m <<= 1) {
            double ov = __shfl_xor(bv, m, 64);
            int oi = __shfl_xor(bi, m, 64);
            if (ov > bv || (ov == bv && oi < bi)) { bv = ov; bi = oi; }
        }
        if (lane == 0) { wv[wid] = bv; wi4[wid] = bi; }
        __syncthreads();
        // all threads compute the global winner redundantly (deterministic)
        double gv = wv[0];
        int gi = wi4[0];
#pragma unroll
        for (int w = 1; w < 4; ++w) {
            if (wv[w] > gv || (wv[w] == gv && wi4[w] < gi)) { gv = wv[w]; gi = wi4[w]; }
        }
        if (tid == 0) { topvS[it] = gv; topiS[it] = gi; }
        // owner invalidates its slot and recomputes local max
        if ((gi & 255) == tid) {
            emask |= 1u << (gi >> 8);
            lv = -INFINITY;
            li = 0x7fffffff;
#pragma unroll
            for (int k = 0; k < 16; ++k) {
                const int j = tid + (k << 8);
                if (!((emask >> k) & 1u) && (v[k] > lv || (v[k] == lv && j < li))) {
                    lv = v[k]; li = j;
                }
            }
        }
        __syncthreads();  // protect wv/wi4 reuse + topvS visibility
    }

    if (tid == 0) {
        double m = topvS[0], s = 0.0;
        for (int t = 0; t < TOPK; ++t) s += exp(topvS[t] - m);
        ssum = s;
    }
    __syncthreads();

    if (tid < TOPK) {
        const int NK = N * TOPK;
        const int base = i * TOPK + tid;
        double w = exp(topvS[tid] - topvS[0]) / ssum;
        out[base] = (float)topiS[tid];        // edge_index row 0: topk column idx
        out[NK + base] = (float)i;            // edge_index row 1: source row
        out[2 * NK + base] = (float)w;        // edge_weight (softmax)
    }
}

extern "C" void kernel_launch(void* const* d_in, const int* in_sizes, int n_in,
                              void* d_out, int out_size, void* d_ws, size_t ws_size,
                              hipStream_t stream) {
    const float* emb    = (const float*)d_in[0];
    const float* W      = (const float*)d_in[1];
    const float* att    = (const float*)d_in[2];
    const float* lam    = (const float*)d_in[3];
    const int*   sector = (const int*)d_in[4];
    const int*   active = (const int*)d_in[5];
    const int*   eidx   = (const int*)d_in[6];
    const float* ew     = (const float*)d_in[7];
    float* out = (float*)d_out;

    const int N = in_sizes[5];      // 4096
    const int E = in_sizes[6] / 2;  // 131072

    // workspace layout (doubles first, then ints)
    double* wa_dst = (double*)d_ws;
    double* wa_src = wa_dst + HEADS * H_DIM;
    double* s_dst  = wa_src + HEADS * H_DIM;
    double* s_src  = s_dst + (size_t)N * HEADS;
    int* row_cnt   = (int*)(s_src + (size_t)N * HEADS);
    int* fill_cnt  = row_cnt + N;
    int* row_off   = fill_cnt + N;
    int* csr_col   = row_off + (N + 2);
    int* csr_eid   = csr_col + E;
    float* csr_w   = (float*)(csr_eid + E);

    hipMemsetAsync(row_cnt, 0, (size_t)2 * N * sizeof(int), stream);  // row_cnt + fill_cnt

    wa_kernel<<<1, 256, 0, stream>>>(W, att, wa_dst, wa_src);
    s_kernel<<<N / 4, 256, 0, stream>>>(emb, wa_dst, wa_src, s_dst, s_src);
    count_kernel<<<(E + 255) / 256, 256, 0, stream>>>(eidx, row_cnt, E);
    scan_kernel<<<1, 256, 0, stream>>>(row_cnt, row_off, N);
    fill_kernel<<<(E + 255) / 256, 256, 0, stream>>>(eidx, ew, row_off, fill_cnt,
                                                     csr_col, csr_eid, csr_w, E);
    main_kernel<<<N, 256, 0, stream>>>(s_dst, s_src, sector, active, lam, row_off,
                                       csr_col, csr_eid, csr_w, out, N);
}

// Round 3
// 366.940 us; speedup vs baseline: 1.4224x; 1.0607x over previous
//
#include <hip/hip_runtime.h>
#include <math.h>

#define H_DIM 256
#define HEADS 4
#define HD 64
#define TOPK 15
#define NSLOPE 0.2
#define EDGE_CAP_MAX 128

// wa_dst[h][k] = sum_d W[(h*64+d)*256+k] * att[h*128+d]      (a_dst)
// wa_src[h][k] = sum_d W[(h*64+d)*256+k] * att[h*128+64+d]   (a_src)
__global__ void wa_kernel(const float* __restrict__ W, const float* __restrict__ att,
                          double* __restrict__ wa_dst, double* __restrict__ wa_src) {
    int k = threadIdx.x;  // 0..255
    for (int h = 0; h < HEADS; ++h) {
        double ad = 0.0, as = 0.0;
        for (int d = 0; d < HD; ++d) {
            double wv = (double)W[(h * HD + d) * H_DIM + k];
            ad += wv * (double)att[h * 2 * HD + d];
            as += wv * (double)att[h * 2 * HD + HD + d];
        }
        wa_dst[h * H_DIM + k] = ad;
        wa_src[h * H_DIM + k] = as;
    }
}

// One wave per row: 8 dot-products of length 256 via shuffle reduce, no barriers.
__global__ __launch_bounds__(256) void s_kernel(const float* __restrict__ emb,
                                                const double* __restrict__ wa_dst,
                                                const double* __restrict__ wa_src,
                                                double* __restrict__ s_dst,
                                                double* __restrict__ s_src) {
    const int lane = threadIdx.x & 63;
    const int wid = threadIdx.x >> 6;
    const int i = blockIdx.x * 4 + wid;
    double e[4];
#pragma unroll
    for (int m = 0; m < 4; ++m) e[m] = (double)emb[(size_t)i * H_DIM + lane + 64 * m];
#pragma unroll
    for (int combo = 0; combo < 8; ++combo) {
        const int h = combo >> 1;
        const double* wa = (combo & 1) ? wa_src : wa_dst;
        double acc = 0.0;
#pragma unroll
        for (int m = 0; m < 4; ++m) acc += e[m] * wa[h * H_DIM + lane + 64 * m];
#pragma unroll
        for (int m = 1; m < 64; m <<= 1) acc += __shfl_xor(acc, m, 64);
        if (lane == 0) {
            if (combo & 1) s_src[i * HEADS + h] = acc;
            else           s_dst[i * HEADS + h] = acc;
        }
    }
}

// One-pass padded-table CSR build: slot append per row via atomicAdd.
// Dedup later is by max edge id, so slot order (nondeterministic) doesn't matter.
__global__ void build_kernel(const int* __restrict__ eidx, const float* __restrict__ ew,
                             int* __restrict__ cnt, int* __restrict__ col_t,
                             int* __restrict__ eid_t, float* __restrict__ w_t,
                             int E, int cap) {
    int e = blockIdx.x * 256 + threadIdx.x;
    if (e < E) {
        int r = eidx[e];
        int c = eidx[E + e];
        int s = atomicAdd(&cnt[r], 1);
        if (s < cap) {
            col_t[r * cap + s] = c;
            eid_t[r * cap + s] = e;
            w_t[r * cap + s] = ew[e];
        }
    }
}

#define FOR16(OP) OP(0) OP(1) OP(2) OP(3) OP(4) OP(5) OP(6) OP(7) \
                  OP(8) OP(9) OP(10) OP(11) OP(12) OP(13) OP(14) OP(15)

__device__ __forceinline__ void argmax64(double& bv, int& bi) {
#pragma unroll
    for (int m = 1; m < 64; m <<= 1) {
        double ov = __shfl_xor(bv, m, 64);
        int oi = __shfl_xor(bi, m, 64);
        if (ov > bv || (ov == bv && oi < bi)) { bv = ov; bi = oi; }
    }
}

// One block per row. 16 named fp64 registers per thread (thread owns columns
// j = tid + 256k). Per-wave barrier-free top-15 (shuffle butterflies), then a
// single-wave 60->15 merge. Only 2 __syncthreads per block.
__global__ __launch_bounds__(256) void main_kernel(
    const double* __restrict__ s_dst, const double* __restrict__ s_src,
    const int* __restrict__ sector_mask, const int* __restrict__ active,
    const float* __restrict__ lam_p, const int* __restrict__ cnt,
    const int* __restrict__ col_t, const int* __restrict__ eid_t,
    const float* __restrict__ w_t, float* __restrict__ out, int N, int cap) {
    const int i = blockIdx.x;
    const int tid = threadIdx.x;
    const int lane = tid & 63;
    const int wid = tid >> 6;

    __shared__ int ec[EDGE_CAP_MAX];
    __shared__ int ee[EDGE_CAP_MAX];
    __shared__ float ewl[EDGE_CAP_MAX];
    __shared__ double cand_v[4 * TOPK];
    __shared__ int cand_i[4 * TOPK];

    const double sd0 = s_dst[i * 4 + 0];
    const double sd1 = s_dst[i * 4 + 1];
    const double sd2 = s_dst[i * 4 + 2];
    const double sd3 = s_dst[i * 4 + 3];
    const bool ai = (active[i] != 0);
    const double lam = (double)lam_p[0];
    const size_t rowbase = (size_t)i * (size_t)N;
    const double4* __restrict__ s_src4 = (const double4*)s_src;

    // Stage this row's edge slice into LDS (cooperative)
    int deg = cnt[i];
    if (deg > cap) deg = cap;
    for (int p = tid; p < deg; p += 256) {
        ec[p] = col_t[i * cap + p];
        ee[p] = eid_t[i * cap + p];
        ewl[p] = w_t[i * cap + p];
    }

    // Phase 1: scores into 16 named registers
    double v0, v1, v2, v3, v4, v5, v6, v7, v8, v9, v10, v11, v12, v13, v14, v15;
#define INIT_SLOT(K) { \
    const int j = tid + (K << 8); \
    const bool m = ai && (active[j] != 0) && (sector_mask[rowbase + j] != 0); \
    const double4 sv = s_src4[j]; \
    double x0 = sd0 + sv.x, x1 = sd1 + sv.y, x2 = sd2 + sv.z, x3 = sd3 + sv.w; \
    x0 = (x0 < 0.0) ? NSLOPE * x0 : x0; \
    x1 = (x1 < 0.0) ? NSLOPE * x1 : x1; \
    x2 = (x2 < 0.0) ? NSLOPE * x2 : x2; \
    x3 = (x3 < 0.0) ? NSLOPE * x3 : x3; \
    v##K = m ? (0.25 * (x0 + x1 + x2 + x3)) : -INFINITY; }
    FOR16(INIT_SLOT)
#undef INIT_SLOT

    __syncthreads();  // edge slice visible

    // Phase 2: corr edges (last-write-wins by edge id; O(deg^2) dedup, deg~32)
    for (int p = 0; p < deg; ++p) {
        const int c = ec[p];
        if ((c & 255) == tid) {
            const int eid = ee[p];
            bool win = true;
            for (int q = 0; q < deg; ++q)
                if (ec[q] == c && ee[q] > eid) win = false;
            if (win) {
                const double add = lam * (double)ewl[p];  // -inf + add stays -inf
                const int kk = c >> 8;
#define ADD_SLOT(K) if (kk == K) v##K += add;
                FOR16(ADD_SLOT)
#undef ADD_SLOT
            }
        }
    }

    // Phase 3: per-thread local max, then per-wave barrier-free top-15
    unsigned int emask = 0;
    double lv = -INFINITY;
    int li = 0x7fffffff;
#define SCAN0(K) { const int j = tid + (K << 8); \
    if (v##K > lv || (v##K == lv && j < li)) { lv = v##K; li = j; } }
    FOR16(SCAN0)
#undef SCAN0

    for (int it = 0; it < TOPK; ++it) {
        double bv = lv;
        int bi = li;
        argmax64(bv, bi);
        if (lane == 0) { cand_v[wid * TOPK + it] = bv; cand_i[wid * TOPK + it] = bi; }
        if ((bi & 255) == tid) {  // owner invalidates + recomputes (1 lane, predicated)
            emask |= 1u << (bi >> 8);
            lv = -INFINITY;
            li = 0x7fffffff;
#define SCAN1(K) { const int j = tid + (K << 8); \
    if (!((emask >> K) & 1u) && (v##K > lv || (v##K == lv && j < li))) { lv = v##K; li = j; } }
            FOR16(SCAN1)
#undef SCAN1
        }
    }
    __syncthreads();  // candidates visible

    // Single-wave merge of 60 candidates -> ordered top-15 + softmax + store
    if (wid == 0) {
        double cv = (lane < 4 * TOPK) ? cand_v[lane] : -INFINITY;
        int ci = (lane < 4 * TOPK) ? cand_i[lane] : 0x7fffffff;
        double fv = -INFINITY;
        int fi = 0;
#pragma unroll
        for (int it = 0; it < TOPK; ++it) {
            double bv = cv;
            int bi = ci;
            argmax64(bv, bi);
            if (ci == bi) cv = -INFINITY;  // indices unique across candidates
            if (lane == it) { fv = bv; fi = bi; }
        }
        const double gmax = __shfl(fv, 0, 64);
        double e = (lane < TOPK) ? exp(fv - gmax) : 0.0;
        double s = e;
#pragma unroll
        for (int m = 1; m < 64; m <<= 1) s += __shfl_xor(s, m, 64);
        if (lane < TOPK) {
            const int NK = N * TOPK;
            const int base = i * TOPK + lane;
            out[base] = (float)fi;             // edge_index row 0: topk column idx
            out[NK + base] = (float)i;         // edge_index row 1: source row
            out[2 * NK + base] = (float)(e / s);  // edge_weight (softmax)
        }
    }
}

extern "C" void kernel_launch(void* const* d_in, const int* in_sizes, int n_in,
                              void* d_out, int out_size, void* d_ws, size_t ws_size,
                              hipStream_t stream) {
    const float* emb    = (const float*)d_in[0];
    const float* W      = (const float*)d_in[1];
    const float* att    = (const float*)d_in[2];
    const float* lam    = (const float*)d_in[3];
    const int*   sector = (const int*)d_in[4];
    const int*   active = (const int*)d_in[5];
    const int*   eidx   = (const int*)d_in[6];
    const float* ew     = (const float*)d_in[7];
    float* out = (float*)d_out;

    const int N = in_sizes[5];      // 4096
    const int E = in_sizes[6] / 2;  // 131072

    // workspace layout
    double* wa_dst = (double*)d_ws;                    // 1024 dbl
    double* wa_src = wa_dst + HEADS * H_DIM;           // 1024 dbl
    double* s_dst  = wa_src + HEADS * H_DIM;           // N*4 dbl
    double* s_src  = s_dst + (size_t)N * HEADS;        // N*4 dbl
    int* cnt       = (int*)(s_src + (size_t)N * HEADS);
    int* col_t     = cnt + N;

    size_t used = (size_t)(2 * HEADS * H_DIM + 2 * (size_t)N * HEADS) * 8 + (size_t)N * 4
                  + 256;  // headroom
    size_t rem = (ws_size > used) ? (ws_size - used) : 0;
    int cap = (int)(rem / ((size_t)N * 12));
    if (cap > EDGE_CAP_MAX) cap = EDGE_CAP_MAX;
    if (cap < 16) cap = 16;

    int* eid_t = col_t + (size_t)N * cap;
    float* w_t = (float*)(eid_t + (size_t)N * cap);

    hipMemsetAsync(cnt, 0, (size_t)N * sizeof(int), stream);

    wa_kernel<<<1, 256, 0, stream>>>(W, att, wa_dst, wa_src);
    s_kernel<<<N / 4, 256, 0, stream>>>(emb, wa_dst, wa_src, s_dst, s_src);
    build_kernel<<<(E + 255) / 256, 256, 0, stream>>>(eidx, ew, cnt, col_t, eid_t, w_t, E, cap);
    main_kernel<<<N, 256, 0, stream>>>(s_dst, s_src, sector, active, lam, cnt,
                                       col_t, eid_t, w_t, out, N, cap);
}

// Round 4
// 223.047 us; speedup vs baseline: 2.3399x; 1.6451x over previous
//
#include <hip/hip_runtime.h>
#include <math.h>

#define H_DIM 256
#define HEADS 4
#define HD 64
#define TOPK 15
#define NSLOPE 0.2
#define EDGE_CAP_MAX 128
#define CAND_CAP 256

// 8 blocks: block b computes wa for head h=b>>1, side=b&1 (0=dst,1=src)
__global__ void wa_kernel(const float* __restrict__ W, const float* __restrict__ att,
                          double* __restrict__ wa_dst, double* __restrict__ wa_src) {
    const int k = threadIdx.x;  // 0..255
    const int h = blockIdx.x >> 1;
    const int side = blockIdx.x & 1;
    double a = 0.0;
    for (int d = 0; d < HD; ++d)
        a += (double)W[(h * HD + d) * H_DIM + k] * (double)att[h * 2 * HD + side * HD + d];
    (side ? wa_src : wa_dst)[h * H_DIM + k] = a;
}

// One wave per row; 8 independent dot-products, butterflies interleaved for ILP.
__global__ __launch_bounds__(256) void s_kernel(const float* __restrict__ emb,
                                                const double* __restrict__ wa_dst,
                                                const double* __restrict__ wa_src,
                                                double* __restrict__ s_dst,
                                                double* __restrict__ s_src) {
    const int lane = threadIdx.x & 63;
    const int wid = threadIdx.x >> 6;
    const int i = blockIdx.x * 4 + wid;
    double e[4];
#pragma unroll
    for (int m = 0; m < 4; ++m) e[m] = (double)emb[(size_t)i * H_DIM + lane + 64 * m];
    double acc[8];
#pragma unroll
    for (int c = 0; c < 8; ++c) {
        const double* wa = (c & 1) ? wa_src : wa_dst;
        const int h = c >> 1;
        double a = 0.0;
#pragma unroll
        for (int m = 0; m < 4; ++m) a += e[m] * wa[h * H_DIM + lane + 64 * m];
        acc[c] = a;
    }
#pragma unroll
    for (int m = 1; m < 64; m <<= 1) {
#pragma unroll
        for (int c = 0; c < 8; ++c) acc[c] += __shfl_xor(acc[c], m, 64);
    }
    if (lane == 0) {
#pragma unroll
        for (int c = 0; c < 8; ++c) {
            double* dst = (c & 1) ? s_src : s_dst;
            dst[i * HEADS + (c >> 1)] = acc[c];
        }
    }
}

// One-pass padded-table CSR build (slot order nondeterministic; dedup is by
// max edge id, which is order-independent).
__global__ void build_kernel(const int* __restrict__ eidx, const float* __restrict__ ew,
                             int* __restrict__ cnt, int* __restrict__ col_t,
                             int* __restrict__ eid_t, float* __restrict__ w_t,
                             int E, int cap) {
    int e = blockIdx.x * 256 + threadIdx.x;
    if (e < E) {
        int r = eidx[e];
        int c = eidx[E + e];
        int s = atomicAdd(&cnt[r], 1);
        if (s < cap) {
            col_t[r * cap + s] = c;
            eid_t[r * cap + s] = e;
            w_t[r * cap + s] = ew[e];
        }
    }
}

#define FOR16(OP) OP(0) OP(1) OP(2) OP(3) OP(4) OP(5) OP(6) OP(7) \
                  OP(8) OP(9) OP(10) OP(11) OP(12) OP(13) OP(14) OP(15)

// One block per row. 16 fp64 scores in named registers (thread owns columns
// j = tid + 256k). Selection: fp32 keys -> per-wave ballot binary-search
// threshold -> candidate filter -> exact fp64 rank-by-counting. No serial
// extraction, 5 barriers, no shuffle chains.
__global__ __launch_bounds__(256) void main_kernel(
    const double* __restrict__ s_dst, const double* __restrict__ s_src,
    const int* __restrict__ sector_mask, const int* __restrict__ active,
    const float* __restrict__ lam_p, const int* __restrict__ cnt,
    const int* __restrict__ col_t, const int* __restrict__ eid_t,
    const float* __restrict__ w_t, float* __restrict__ out, int N, int cap) {
    const int i = blockIdx.x;
    const int tid = threadIdx.x;
    const int lane = tid & 63;
    const int wid = tid >> 6;

    __shared__ int ec[EDGE_CAP_MAX];
    __shared__ int ee[EDGE_CAP_MAX];
    __shared__ float ewl[EDGE_CAP_MAX];
    __shared__ int wcol[EDGE_CAP_MAX];
    __shared__ double wadd[EDGE_CAP_MAX];
    __shared__ unsigned int wth[4];
    __shared__ double cand_v[CAND_CAP];
    __shared__ int cand_i[CAND_CAP];
    __shared__ int cand_cnt, wcnt;
    __shared__ double sorted_v[TOPK];
    __shared__ int sorted_i[TOPK];
    __shared__ double exps[TOPK];

    if (tid == 0) { cand_cnt = 0; wcnt = 0; }

    // Stage this row's edge slice into LDS
    int deg = cnt[i];
    if (deg > cap) deg = cap;
    for (int p = tid; p < deg; p += 256) {
        ec[p] = col_t[i * cap + p];
        ee[p] = eid_t[i * cap + p];
        ewl[p] = w_t[i * cap + p];
    }

    const double sd0 = s_dst[i * 4 + 0];
    const double sd1 = s_dst[i * 4 + 1];
    const double sd2 = s_dst[i * 4 + 2];
    const double sd3 = s_dst[i * 4 + 3];
    const bool ai = (active[i] != 0);
    const double lam = (double)lam_p[0];
    const size_t rowbase = (size_t)i * (size_t)N;
    const double4* __restrict__ s_src4 = (const double4*)s_src;

    // Phase 1: scores into 16 named fp64 registers
    double v0, v1, v2, v3, v4, v5, v6, v7, v8, v9, v10, v11, v12, v13, v14, v15;
#define INIT_SLOT(K) { \
    const int j = tid + (K << 8); \
    const bool m = ai && (active[j] != 0) && (sector_mask[rowbase + j] != 0); \
    const double4 sv = s_src4[j]; \
    double x0 = sd0 + sv.x, x1 = sd1 + sv.y, x2 = sd2 + sv.z, x3 = sd3 + sv.w; \
    x0 = (x0 < 0.0) ? NSLOPE * x0 : x0; \
    x1 = (x1 < 0.0) ? NSLOPE * x1 : x1; \
    x2 = (x2 < 0.0) ? NSLOPE * x2 : x2; \
    x3 = (x3 < 0.0) ? NSLOPE * x3 : x3; \
    v##K = m ? (0.25 * (x0 + x1 + x2 + x3)) : -INFINITY; }
    FOR16(INIT_SLOT)
#undef INIT_SLOT

    __syncthreads();  // edges + counters visible

    // Phase 2a: parallel dedup (last-write-wins by edge id), thread-per-edge
    if (tid < deg) {
        const int c = ec[tid];
        const int eid = ee[tid];
        bool win = true;
        for (int q = 0; q < deg; ++q)
            if (ec[q] == c && ee[q] > eid) win = false;
        if (win) {
            int p = atomicAdd(&wcnt, 1);
            wcol[p] = c;
            wadd[p] = lam * (double)ewl[tid];
        }
    }
    __syncthreads();

    // Phase 2b: owners apply winner adds (-inf + add stays -inf)
    const int nw = wcnt;
    for (int w = 0; w < nw; ++w) {
        const int c = wcol[w];
        if ((c & 255) == tid) {
            const double add = wadd[w];
            const int kk = c >> 8;
#define ADD_SLOT(K) if (kk == K) v##K += add;
            FOR16(ADD_SLOT)
#undef ADD_SLOT
        }
    }

    // Phase 3a: fp32 monotone keys + per-thread local max
    unsigned int k0, k1, k2, k3, k4, k5, k6, k7, k8, k9, k10, k11, k12, k13, k14, k15;
#define KEY_SLOT(K) { const float f = (float)v##K; const unsigned u = __float_as_uint(f); \
    k##K = u ^ ((unsigned)((int)u >> 31) | 0x80000000u); }
    FOR16(KEY_SLOT)
#undef KEY_SLOT
    unsigned int lmax = k0;
#define LMAX(K) if (k##K > lmax) lmax = k##K;
    FOR16(LMAX)
#undef LMAX

    // Phase 3b: per-wave 15th-largest lane-max via ballot binary search
    // (valid lower bound on the row's true 15th value; see round theory)
    unsigned int th = 0;
    for (int b = 31; b >= 0; --b) {
        const unsigned int trial = th | (1u << b);
        unsigned long long m = __ballot(lmax >= trial);
        if (__popcll(m) >= TOPK) th = trial;
    }
    if (lane == 0) wth[wid] = th;
    __syncthreads();
    th = wth[0];
    if (wth[1] > th) th = wth[1];
    if (wth[2] > th) th = wth[2];
    if (wth[3] > th) th = wth[3];

    // Phase 3c: candidate filter (superset of true top-15 by monotonicity)
#define FILT(K) if (k##K >= th) { int p = atomicAdd(&cand_cnt, 1); \
    if (p < CAND_CAP) { cand_v[p] = v##K; cand_i[p] = tid + (K << 8); } }
    FOR16(FILT)
#undef FILT
    __syncthreads();

    // Phase 4: exact fp64 rank-by-counting among C candidates (unique ranks)
    int C = cand_cnt;
    if (C > CAND_CAP) C = CAND_CAP;
    if (tid < C) {
        const double mv = cand_v[tid];
        const int mi = cand_i[tid];
        int rank = 0;
        for (int q = 0; q < C; ++q) {
            const double qv = cand_v[q];
            const int qi = cand_i[q];
            rank += ((qv > mv) || (qv == mv && qi < mi)) ? 1 : 0;
        }
        if (rank < TOPK) { sorted_v[rank] = mv; sorted_i[rank] = mi; }
    }
    __syncthreads();

    // Phase 5: softmax + store
    if (tid < TOPK) exps[tid] = exp(sorted_v[tid] - sorted_v[0]);
    __syncthreads();
    if (tid < TOPK) {
        double s = 0.0;
        for (int t = 0; t < TOPK; ++t) s += exps[t];
        const int NK = N * TOPK;
        const int base = i * TOPK + tid;
        out[base] = (float)sorted_i[tid];      // edge_index row 0: topk column idx
        out[NK + base] = (float)i;             // edge_index row 1: source row
        out[2 * NK + base] = (float)(exps[tid] / s);  // edge_weight (softmax)
    }
}

extern "C" void kernel_launch(void* const* d_in, const int* in_sizes, int n_in,
                              void* d_out, int out_size, void* d_ws, size_t ws_size,
                              hipStream_t stream) {
    const float* emb    = (const float*)d_in[0];
    const float* W      = (const float*)d_in[1];
    const float* att    = (const float*)d_in[2];
    const float* lam    = (const float*)d_in[3];
    const int*   sector = (const int*)d_in[4];
    const int*   active = (const int*)d_in[5];
    const int*   eidx   = (const int*)d_in[6];
    const float* ew     = (const float*)d_in[7];
    float* out = (float*)d_out;

    const int N = in_sizes[5];      // 4096
    const int E = in_sizes[6] / 2;  // 131072

    // workspace layout
    double* wa_dst = (double*)d_ws;                    // 1024 dbl
    double* wa_src = wa_dst + HEADS * H_DIM;           // 1024 dbl
    double* s_dst  = wa_src + HEADS * H_DIM;           // N*4 dbl
    double* s_src  = s_dst + (size_t)N * HEADS;        // N*4 dbl
    int* cnt       = (int*)(s_src + (size_t)N * HEADS);
    int* col_t     = cnt + N;

    size_t used = (size_t)(2 * HEADS * H_DIM + 2 * (size_t)N * HEADS) * 8 + (size_t)N * 4
                  + 256;  // headroom
    size_t rem = (ws_size > used) ? (ws_size - used) : 0;
    int cap = (int)(rem / ((size_t)N * 12));
    if (cap > EDGE_CAP_MAX) cap = EDGE_CAP_MAX;
    if (cap < 16) cap = 16;

    int* eid_t = col_t + (size_t)N * cap;
    float* w_t = (float*)(eid_t + (size_t)N * cap);

    hipMemsetAsync(cnt, 0, (size_t)N * sizeof(int), stream);

    wa_kernel<<<2 * HEADS, 256, 0, stream>>>(W, att, wa_dst, wa_src);
    s_kernel<<<N / 4, 256, 0, stream>>>(emb, wa_dst, wa_src, s_dst, s_src);
    build_kernel<<<(E + 255) / 256, 256, 0, stream>>>(eidx, ew, cnt, col_t, eid_t, w_t, E, cap);
    main_kernel<<<N, 256, 0, stream>>>(s_dst, s_src, sector, active, lam, cnt,
                                       col_t, eid_t, w_t, out, N, cap);
}